// Round 4
// baseline (238.059 us; speedup 1.0000x reference)
//
#include <hip/hip_runtime.h>

typedef __attribute__((ext_vector_type(8))) short short8;
typedef __attribute__((ext_vector_type(4))) short short4v;
typedef __attribute__((ext_vector_type(4))) float floatx4;

// fp32 -> bf16 bits, round-to-nearest-even (finite inputs only)
__device__ inline short to_bf16s(float f) {
    unsigned u = __builtin_bit_cast(unsigned, f);
    unsigned r = u + 0x7FFFu + ((u >> 16) & 1u);
    return (short)(r >> 16);
}

// async 16B global -> LDS DMA (wave-uniform base + lane*16; lane-ordered layout)
__device__ inline void dma16(const short* g, short* l) {
    __builtin_amdgcn_global_load_lds(
        (const __attribute__((address_space(1))) unsigned int*)(const void*)g,
        (__attribute__((address_space(3))) unsigned int*)(void*)l,
        16, 0, 0);
}

// ---------------------------------------------------------------------------
// 8-element k-contiguous fragment loader -> bf16 bits
// ---------------------------------------------------------------------------
template <typename T> struct Ld8;
template <> struct Ld8<short> {
    static __device__ inline short8 load(const short* p) { return *(const short8*)p; }
};
template <> struct Ld8<float> {
    static __device__ inline short8 load(const float* p) {
        float4 f0 = *(const float4*)p;
        float4 f1 = *(const float4*)(p + 4);
        short8 r;
        r[0] = to_bf16s(f0.x); r[1] = to_bf16s(f0.y);
        r[2] = to_bf16s(f0.z); r[3] = to_bf16s(f0.w);
        r[4] = to_bf16s(f1.x); r[5] = to_bf16s(f1.y);
        r[6] = to_bf16s(f1.z); r[7] = to_bf16s(f1.w);
        return r;
    }
};

// ---------------------------------------------------------------------------
// prep: blocks [0,2048): adjS[row] = adj[row] * (1/max(rowsum,1)), fp32->bf16.
//       blocks [2048,2528): weight transposes into W2T, W1T, BigB[3].
// BigB_l [128][640]: cols kc*128+k = Wr_l[k][j] (kc=0..3), cols 512+k = Wo_l[k][j].
// (unchanged — summation order preserved so absmax stays bit-identical)
// ---------------------------------------------------------------------------
struct PrepArgs {
    const float* adj;
    const float* W2; const float* W1;
    const float* Wr0; const float* Wo0;
    const float* Wr1; const float* Wo1;
    const float* Wr2; const float* Wo2;
    short* adjS; short* W2T; short* W1T;
    short* BigB0; short* BigB1; short* BigB2;
};

__global__ __launch_bounds__(256) void prep(PrepArgs p) {
    int bid = blockIdx.x;
    if (bid < 2048) {
        const float* src = p.adj + (size_t)bid * 2048;
        float s = 0.f;
        for (int c = threadIdx.x; c < 2048; c += 256) s += src[c];
        __shared__ float red[256];
        red[threadIdx.x] = s;
        __syncthreads();
        for (int st = 128; st > 0; st >>= 1) {
            if (threadIdx.x < st) red[threadIdx.x] += red[threadIdx.x + st];
            __syncthreads();
        }
        float d = red[0];
        d = d < 1.f ? 1.f : d;
        float inv = 1.f / d;
        short* dst = p.adjS + (size_t)bid * 2048;
        for (int c = threadIdx.x; c < 2048; c += 256) dst[c] = to_bf16s(src[c] * inv);
        return;
    }
    int t = bid - 2048;
    __shared__ short tile[32][33];
    int tx = threadIdx.x & 31, ty0 = threadIdx.x >> 5;
    const float* in; int C_; int bx, by;
    short* outp; int outld, copies, copystride, outofs;
    if (t < 192) {  // W2 [1536][128] -> W2T [128][1536]
        bx = (t & 3) * 32; by = (t >> 2) * 32; in = p.W2; C_ = 128;
        outp = p.W2T; outld = 1536; copies = 1; copystride = 0; outofs = 0;
    } else if (t < 384) {  // W1 [128][1536] -> W1T [1536][128]
        int u = t - 192; bx = (u % 48) * 32; by = (u / 48) * 32; in = p.W1; C_ = 1536;
        outp = p.W1T; outld = 128; copies = 1; copystride = 0; outofs = 0;
    } else {  // Wr/Wo [128][128] -> BigB_l
        int u = t - 384; int l = u / 32; int v = u % 32;
        const float* Wr[3] = {p.Wr0, p.Wr1, p.Wr2};
        const float* Wo[3] = {p.Wo0, p.Wo1, p.Wo2};
        short* BB[3] = {p.BigB0, p.BigB1, p.BigB2};
        outp = BB[l]; outld = 640; C_ = 128;
        if (v < 16) { in = Wr[l]; bx = (v & 3) * 32; by = (v >> 2) * 32;
                      copies = 4; copystride = 128; outofs = 0; }
        else { v -= 16; in = Wo[l]; bx = (v & 3) * 32; by = (v >> 2) * 32;
               copies = 1; copystride = 0; outofs = 512; }
    }
    for (int i = ty0; i < 32; i += 8)
        tile[i][tx] = to_bf16s(in[(size_t)(by + i) * C_ + bx + tx]);
    __syncthreads();
    for (int i = ty0; i < 32; i += 8) {
        short v = tile[tx][i];
        for (int c = 0; c < copies; ++c)
            outp[(size_t)(bx + i) * outld + (by + tx) + outofs + c * copystride] = v;
    }
}

#define LDSTR 72

// ---------------------------------------------------------------------------
// gemmT: C = A[M,K] @ B[N,K]^T, 16x64 tile, BK=64, reg-prefetch dbuf LDS,
// one barrier per K-step. grid (M/16, N/64) = 1024 blocks -> 4 blocks/CU
// (16 waves/CU) for latency hiding. Each wave owns one 16x16 output frag
// (col block w*16). Same K order as before -> bit-identical results.
// Epilogue: +bias, optional relu, optional rowmap, colofs, bf16 out.
// rowmap=1: row m=b*2048+n -> orow n*4+b.
// HTW: also write HT[(b*128+col)*2048 + n] directly from registers.
// ---------------------------------------------------------------------------
template <typename TA, int RELU, int ROWMAP, int HTW>
__global__ __launch_bounds__(256) void gemmT(
    const TA* __restrict__ A, int lda,
    const short* __restrict__ B, int ldb, int kTiles,
    const float* __restrict__ bias,
    short* __restrict__ C, int ldc, int colofs,
    short* __restrict__ HT) {
    __shared__ __align__(16) short lds[2 * 80 * LDSTR];  // per buf: A 16x72, B 64x72

    int tid = threadIdx.x;
    int blockM = blockIdx.x * 16;
    int blockN = blockIdx.y * 64;

    int srow = tid >> 3;          // A row 0..15 (tid<128); B rows srow, srow+32
    int scol = (tid & 7) * 8;

    const TA* Abase = A + (size_t)blockM * lda;
    const short* Bbase = B + (size_t)blockN * ldb;

    short8 ra, rb0, rb1;
    if (tid < 128) ra = Ld8<TA>::load(Abase + (size_t)srow * lda + scol);
    rb0 = Ld8<short>::load(Bbase + (size_t)srow * ldb + scol);
    rb1 = Ld8<short>::load(Bbase + (size_t)(srow + 32) * ldb + scol);

    floatx4 acc;
    #pragma unroll
    for (int r = 0; r < 4; ++r) acc[r] = 0.f;

    int lane = tid & 63;
    int w = tid >> 6;             // wave -> col block w*16
    int quad = lane >> 4, l15 = lane & 15;

    for (int it = 0; it < kTiles; ++it) {
        short* As = lds + (it & 1) * (80 * LDSTR);
        short* Bs = As + 16 * LDSTR;
        if (tid < 128) *(short8*)(As + srow * LDSTR + scol) = ra;
        *(short8*)(Bs + srow * LDSTR + scol) = rb0;
        *(short8*)(Bs + (srow + 32) * LDSTR + scol) = rb1;
        __syncthreads();
        if (it + 1 < kTiles) {
            int ko = (it + 1) * 64;
            if (tid < 128) ra = Ld8<TA>::load(Abase + (size_t)srow * lda + ko + scol);
            rb0 = Ld8<short>::load(Bbase + (size_t)srow * ldb + ko + scol);
            rb1 = Ld8<short>::load(Bbase + (size_t)(srow + 32) * ldb + ko + scol);
        }
        const short* Arow = As + l15 * LDSTR;
        const short* Brow = Bs + (w * 16 + l15) * LDSTR;
        #pragma unroll
        for (int ks = 0; ks < 2; ++ks) {
            int kof = ks * 32 + quad * 8;
            short8 a0 = *(const short8*)(Arow + kof);
            short8 b0 = *(const short8*)(Brow + kof);
            acc = __builtin_amdgcn_mfma_f32_16x16x32_bf16(a0, b0, acc, 0, 0, 0);
        }
        // no trailing barrier: double-buffered
    }

    int col = blockN + w * 16 + l15;
    float bv = bias[col];
    int m0 = blockM + quad * 4;   // 4-aligned
    short4v pk;
    #pragma unroll
    for (int r = 0; r < 4; ++r) {
        int m = m0 + r;
        float xv = acc[r] + bv;
        if (RELU) xv = xv > 0.f ? xv : 0.f;
        short v = to_bf16s(xv);
        pk[r] = v;
        int orow = ROWMAP ? (((m & 2047) << 2) | (m >> 11)) : m;
        C[(size_t)orow * ldc + col + colofs] = v;
        if (HTW && !ROWMAP) {
            // rows are n*4+b; b=m&3, n=m>>2
            HT[(size_t)((m & 3) * 128 + col) * 2048 + (m >> 2)] = v;
        }
    }
    if (HTW && ROWMAP) {
        // rows are b*2048+n; 4 consecutive n share b -> packed 8B store
        int b = m0 >> 11, n0 = m0 & 2047;
        *(short4v*)(HT + (size_t)(b * 128 + col) * 2048 + n0) = pk;
    }
}

// ---------------------------------------------------------------------------
// gemmS: adjacency GEMM partials. 32x128 tile, BK=64, global_load_lds 16B,
// 2-phase double-buffer (stage(it+1) issued before compute(it), one barrier
// per iter). A = adjS [2048][2048], B = HT [512][2048], K-chunk = z*512.
// Writes big[l][(m*4 + j>>7)*640 + (j&127) + z*128] (bf16) — z-partials are
// summed implicitly by the next gemmT via the 4x-replicated Wr in BigB.
// grid (64,4,4) = 1024 blocks, LDS 40KB -> 4 blocks/CU (160KB exactly).
// Wave w owns col block w*32 (2 frags) x 2 row frags.
// ---------------------------------------------------------------------------
__global__ __launch_bounds__(256) void gemmS(const short* __restrict__ A,
                                             const short* __restrict__ B,
                                             short* __restrict__ C) {
    __shared__ __align__(16) short As[2][32 * 64];
    __shared__ __align__(16) short Bs[2][128 * 64];

    int tid = threadIdx.x;
    int kz = blockIdx.z * 512;

    const short* Ab = A + (size_t)(blockIdx.x * 32 + (tid >> 3)) * 2048 + kz + (tid & 7) * 8;
    const short* Bb = B + (size_t)(blockIdx.y * 128 + (tid >> 3)) * 2048 + kz + (tid & 7) * 8;

    floatx4 acc[2][2];
    #pragma unroll
    for (int i = 0; i < 2; ++i)
        #pragma unroll
        for (int j = 0; j < 2; ++j)
            #pragma unroll
            for (int r = 0; r < 4; ++r) acc[i][j][r] = 0.f;

    int lane = tid & 63;
    int w = tid >> 6;             // wave -> col block w*32
    int quad = lane >> 4, l15 = lane & 15;

    auto stage = [&](int p, int it) {
        const short* Ag = Ab + it * 64;
        const short* Bg = Bb + it * 64;
        dma16(Ag, &As[p][tid * 8]);                       // 32 rows x 64
        #pragma unroll
        for (int r = 0; r < 4; ++r)
            dma16(Bg + (size_t)r * 32 * 2048, &Bs[p][tid * 8 + r * 2048]);  // 128 rows
    };

    stage(0, 0);
    __syncthreads();  // drains vmcnt(0): tile 0 visible

    for (int it = 0; it < 8; ++it) {
        int p = it & 1;
        if (it + 1 < 8) stage(p ^ 1, it + 1);  // in flight during compute
        const short* Ar = &As[p][l15 * 64];
        const short* Br = &Bs[p][(w * 32 + l15) * 64];
        #pragma unroll
        for (int ks = 0; ks < 2; ++ks) {
            int kof = ks * 32 + quad * 8;
            short8 af[2], bfr[2];
            af[0]  = *(const short8*)(Ar + kof);
            af[1]  = *(const short8*)(Ar + 16 * 64 + kof);
            bfr[0] = *(const short8*)(Br + kof);
            bfr[1] = *(const short8*)(Br + 16 * 64 + kof);
            #pragma unroll
            for (int i = 0; i < 2; ++i)
                #pragma unroll
                for (int j = 0; j < 2; ++j)
                    acc[i][j] = __builtin_amdgcn_mfma_f32_16x16x32_bf16(af[i], bfr[j], acc[i][j], 0, 0, 0);
        }
        __syncthreads();  // next tile's DMA landed; all waves done reading p
    }

    int colofs = blockIdx.z * 128;
    #pragma unroll
    for (int ti = 0; ti < 2; ++ti) {
        #pragma unroll
        for (int tj = 0; tj < 2; ++tj) {
            int j = blockIdx.y * 128 + w * 32 + tj * 16 + l15;  // 0..511 = b*128+d
            int jhi = j >> 7, jlo = j & 127;
            int row0 = blockIdx.x * 32 + ti * 16 + quad * 4;
            #pragma unroll
            for (int r = 0; r < 4; ++r) {
                int m = row0 + r;  // node n
                C[(size_t)(m * 4 + jhi) * 640 + jlo + colofs] = to_bf16s(acc[ti][tj][r]);
            }
        }
    }
}

// ---------------------------------------------------------------------------
// gemmL: mlp1. 64x64 tile, K=128 staged whole into LDS (32KB), one barrier,
// then 4 uninterrupted k-steps. grid (128,24) = 3072 blocks -> 5 blocks/CU.
// A = big3+512 (rows n*4+b, lda 640), B = W1T [1536][128].
// fp32 out with +bias, row (n*4+b) -> b*2048+n. Same K order as before.
// Wave w owns rows w*16 x all 64 cols (4 col frags).
// ---------------------------------------------------------------------------
__global__ __launch_bounds__(256) void gemmL(const short* __restrict__ A,
                                             const short* __restrict__ B,
                                             const float* __restrict__ bias,
                                             float* __restrict__ C) {
    __shared__ __align__(16) short As[64 * 128];
    __shared__ __align__(16) short Bs[64 * 128];

    int tid = threadIdx.x;
    int blockM = blockIdx.x * 64;
    int blockN = blockIdx.y * 64;

    #pragma unroll
    for (int r = 0; r < 4; ++r) {
        int s = tid + 256 * r;           // 0..1023: row = s>>4, kgrp = s&15
        int row = s >> 4, grp = (s & 15) * 8;
        dma16(A + (size_t)(blockM + row) * 640 + grp, &As[s * 8]);
        dma16(B + (size_t)(blockN + row) * 128 + grp, &Bs[s * 8]);
    }

    floatx4 acc[4];
    #pragma unroll
    for (int j = 0; j < 4; ++j)
        #pragma unroll
        for (int r = 0; r < 4; ++r) acc[j][r] = 0.f;

    int lane = tid & 63;
    int w = tid >> 6;
    int quad = lane >> 4, l15 = lane & 15;

    __syncthreads();  // drains vmcnt(0): whole K-panel visible

    const short* Ar = As + (w * 16 + l15) * 128;
    #pragma unroll
    for (int t = 0; t < 4; ++t) {
        int kof = t * 32 + quad * 8;
        short8 a0 = *(const short8*)(Ar + kof);
        #pragma unroll
        for (int j = 0; j < 4; ++j) {
            short8 b = *(const short8*)(Bs + (j * 16 + l15) * 128 + kof);
            acc[j] = __builtin_amdgcn_mfma_f32_16x16x32_bf16(a0, b, acc[j], 0, 0, 0);
        }
    }

    #pragma unroll
    for (int tj = 0; tj < 4; ++tj) {
        int col = blockN + tj * 16 + l15;
        float bv = bias[col];
        int row0 = blockM + w * 16 + quad * 4;
        #pragma unroll
        for (int r = 0; r < 4; ++r) {
            int mp = row0 + r;  // n*4+b
            int orow = ((mp & 3) << 11) | (mp >> 2);
            C[(size_t)orow * 1536 + col] = acc[tj][r] + bv;
        }
    }
}

// ---------------------------------------------------------------------------
// Launch
// ---------------------------------------------------------------------------
extern "C" void kernel_launch(void* const* d_in, const int* in_sizes, int n_in,
                              void* d_out, int out_size, void* d_ws, size_t ws_size,
                              hipStream_t stream) {
    const float* x      = (const float*)d_in[0];
    const float* adj    = (const float*)d_in[1];
    const float* W_mlp2 = (const float*)d_in[2];
    const float* b_mlp2 = (const float*)d_in[3];
    const float* Wr1    = (const float*)d_in[4];
    const float* Wo1    = (const float*)d_in[5];
    const float* b1     = (const float*)d_in[6];
    const float* Wr2    = (const float*)d_in[7];
    const float* Wo2    = (const float*)d_in[8];
    const float* b2     = (const float*)d_in[9];
    const float* Wr3    = (const float*)d_in[10];
    const float* Wo3    = (const float*)d_in[11];
    const float* b3     = (const float*)d_in[12];
    const float* W_mlp1 = (const float*)d_in[13];
    const float* b_mlp1 = (const float*)d_in[14];
    float* out = (float*)d_out;

    char* ws = (char*)d_ws;
    size_t off = 0;
    auto alloc = [&](size_t bytes) -> char* {
        char* p = ws + off;
        off = (off + bytes + 255) & ~(size_t)255;
        return p;
    };
    short* W2T  = (short*)alloc(128 * 1536 * 2);
    short* W1T  = (short*)alloc(1536 * 128 * 2);
    short* BigB[3];
    for (int l = 0; l < 3; ++l) BigB[l] = (short*)alloc(128 * 640 * 2);
    short* adjS = (short*)alloc((size_t)2048 * 2048 * 2);
    short* big[4];
    for (int l = 0; l < 4; ++l) big[l] = (short*)alloc((size_t)8192 * 640 * 2);
    short* HT = (short*)alloc((size_t)512 * 2048 * 2);

    dim3 blk(256);

    PrepArgs pa{adj, W_mlp2, W_mlp1, Wr1, Wo1, Wr2, Wo2, Wr3, Wo3,
                adjS, W2T, W1T, BigB[0], BigB[1], BigB[2]};
    prep<<<2528, blk, 0, stream>>>(pa);

    // mlp2: big0[n*4+b][512+d] = x[b*2048+n] @ W2 + b2, fused HT write
    // (M=8192, K=1536, N=128) grid (512,2)=1024 -> 4 blocks/CU
    gemmT<float, 0, 1, 1><<<dim3(512, 2), blk, 0, stream>>>(
        x, 1536, W2T, 1536, 24, b_mlp2, big[0], 640, 512, HT);

    for (int l = 0; l < 3; ++l) {
        // big_l[:,0:512] = adjS @ Hp_l partials in 4 K-chunks  (M=2048,N=512,K=2048)
        gemmS<<<dim3(64, 4, 4), blk, 0, stream>>>(adjS, HT, big[l]);
        // Hp_{l+1} = act(big_l @ BigB_l^T + b_l)  (M=8192,N=128,K=640), fused HT
        if (l == 0)
            gemmT<short, 1, 0, 1><<<dim3(512, 2), blk, 0, stream>>>(
                big[0], 640, BigB[0], 640, 10, b1, big[1], 640, 512, HT);
        else if (l == 1)
            gemmT<short, 1, 0, 1><<<dim3(512, 2), blk, 0, stream>>>(
                big[1], 640, BigB[1], 640, 10, b2, big[2], 640, 512, HT);
        else
            gemmT<short, 0, 0, 0><<<dim3(512, 2), blk, 0, stream>>>(
                big[2], 640, BigB[2], 640, 10, b3, big[3], 640, 512, nullptr);
    }

    // mlp1: out[b*2048+n] = Hp3 @ W1 + b1   (M=8192,N=1536,K=128)
    gemmL<<<dim3(128, 24), blk, 0, stream>>>(big[3] + 512, W1T, b_mlp1, out);
}

// Round 6
// 219.891 us; speedup vs baseline: 1.0826x; 1.0826x over previous
//
#include <hip/hip_runtime.h>

typedef __attribute__((ext_vector_type(8))) short short8;
typedef __attribute__((ext_vector_type(4))) short short4v;
typedef __attribute__((ext_vector_type(4))) float floatx4;

// fp32 -> bf16 bits, round-to-nearest-even (finite inputs only)
__device__ inline short to_bf16s(float f) {
    unsigned u = __builtin_bit_cast(unsigned, f);
    unsigned r = u + 0x7FFFu + ((u >> 16) & 1u);
    return (short)(r >> 16);
}

// async 16B global -> LDS DMA (wave-uniform base + lane*16; lane-ordered layout)
__device__ inline void dma16(const short* g, short* l) {
    __builtin_amdgcn_global_load_lds(
        (const __attribute__((address_space(1))) unsigned int*)(const void*)g,
        (__attribute__((address_space(3))) unsigned int*)(void*)l,
        16, 0, 0);
}

// ---------------------------------------------------------------------------
// 8-element k-contiguous fragment loader -> bf16 bits
// ---------------------------------------------------------------------------
template <typename T> struct Ld8;
template <> struct Ld8<short> {
    static __device__ inline short8 load(const short* p) { return *(const short8*)p; }
};
template <> struct Ld8<float> {
    static __device__ inline short8 load(const float* p) {
        float4 f0 = *(const float4*)p;
        float4 f1 = *(const float4*)(p + 4);
        short8 r;
        r[0] = to_bf16s(f0.x); r[1] = to_bf16s(f0.y);
        r[2] = to_bf16s(f0.z); r[3] = to_bf16s(f0.w);
        r[4] = to_bf16s(f1.x); r[5] = to_bf16s(f1.y);
        r[6] = to_bf16s(f1.z); r[7] = to_bf16s(f1.w);
        return r;
    }
};

// ---------------------------------------------------------------------------
// prep: blocks [0,2048): adjS[row] = adj[row] * (1/max(rowsum,1)), fp32->bf16.
//       blocks [2048,2528): weight transposes into W2T, W1T, BigB[3].
// BigB_l [128][640]: cols kc*128+k = Wr_l[k][j] (kc=0..3), cols 512+k = Wo_l[k][j].
// (unchanged — summation order preserved so absmax stays bit-identical)
// ---------------------------------------------------------------------------
struct PrepArgs {
    const float* adj;
    const float* W2; const float* W1;
    const float* Wr0; const float* Wo0;
    const float* Wr1; const float* Wo1;
    const float* Wr2; const float* Wo2;
    short* adjS; short* W2T; short* W1T;
    short* BigB0; short* BigB1; short* BigB2;
};

__global__ __launch_bounds__(256) void prep(PrepArgs p) {
    int bid = blockIdx.x;
    if (bid < 2048) {
        const float* src = p.adj + (size_t)bid * 2048;
        float s = 0.f;
        for (int c = threadIdx.x; c < 2048; c += 256) s += src[c];
        __shared__ float red[256];
        red[threadIdx.x] = s;
        __syncthreads();
        for (int st = 128; st > 0; st >>= 1) {
            if (threadIdx.x < st) red[threadIdx.x] += red[threadIdx.x + st];
            __syncthreads();
        }
        float d = red[0];
        d = d < 1.f ? 1.f : d;
        float inv = 1.f / d;
        short* dst = p.adjS + (size_t)bid * 2048;
        for (int c = threadIdx.x; c < 2048; c += 256) dst[c] = to_bf16s(src[c] * inv);
        return;
    }
    int t = bid - 2048;
    __shared__ short tile[32][33];
    int tx = threadIdx.x & 31, ty0 = threadIdx.x >> 5;
    const float* in; int C_; int bx, by;
    short* outp; int outld, copies, copystride, outofs;
    if (t < 192) {  // W2 [1536][128] -> W2T [128][1536]
        bx = (t & 3) * 32; by = (t >> 2) * 32; in = p.W2; C_ = 128;
        outp = p.W2T; outld = 1536; copies = 1; copystride = 0; outofs = 0;
    } else if (t < 384) {  // W1 [128][1536] -> W1T [1536][128]
        int u = t - 192; bx = (u % 48) * 32; by = (u / 48) * 32; in = p.W1; C_ = 1536;
        outp = p.W1T; outld = 128; copies = 1; copystride = 0; outofs = 0;
    } else {  // Wr/Wo [128][128] -> BigB_l
        int u = t - 384; int l = u / 32; int v = u % 32;
        const float* Wr[3] = {p.Wr0, p.Wr1, p.Wr2};
        const float* Wo[3] = {p.Wo0, p.Wo1, p.Wo2};
        short* BB[3] = {p.BigB0, p.BigB1, p.BigB2};
        outp = BB[l]; outld = 640; C_ = 128;
        if (v < 16) { in = Wr[l]; bx = (v & 3) * 32; by = (v >> 2) * 32;
                      copies = 4; copystride = 128; outofs = 0; }
        else { v -= 16; in = Wo[l]; bx = (v & 3) * 32; by = (v >> 2) * 32;
               copies = 1; copystride = 0; outofs = 512; }
    }
    for (int i = ty0; i < 32; i += 8)
        tile[i][tx] = to_bf16s(in[(size_t)(by + i) * C_ + bx + tx]);
    __syncthreads();
    for (int i = ty0; i < 32; i += 8) {
        short v = tile[tx][i];
        for (int c = 0; c < copies; ++c)
            outp[(size_t)(bx + i) * outld + (by + tx) + outofs + c * copystride] = v;
    }
}

#define LDSTR 72

// ---------------------------------------------------------------------------
// gemmT: C = A[M,K] @ B[N,K]^T, 32x64 tile, BK=64. DRAIN-FREE pipeline:
//  - 2-iteration-deep register prefetch (two named sets, unroll-by-2 loop)
//  - raw s_barrier preceded only by s_waitcnt lgkmcnt(0) (ds_writes visible);
//    prefetched GLOBAL loads stay in flight across barriers (no vmcnt drain).
//  - double-buffered LDS; one barrier per logical iter (store(it+2,buf p) is
//    fenced from compute(it,buf p) by barrier(it+1)).
// Same fragment values + k-order as R1 -> bit-identical results.
// Epilogue: +bias, optional relu, optional rowmap, colofs, bf16 out.
// rowmap=1: row m=b*2048+n -> orow n*4+b.
// HTW: also write HT[(b*128+col)*2048 + n] directly from registers.
// ---------------------------------------------------------------------------
template <typename TA, int RELU, int ROWMAP, int HTW>
__global__ __launch_bounds__(256) void gemmT(
    const TA* __restrict__ A, int lda,
    const short* __restrict__ B, int ldb, int kTiles,
    const float* __restrict__ bias,
    short* __restrict__ C, int ldc, int colofs,
    short* __restrict__ HT) {
    __shared__ __align__(16) short lds[2 * 96 * LDSTR];

    int tid = threadIdx.x;
    int blockM = blockIdx.x * 32;
    int blockN = blockIdx.y * 64;

    int srow = tid >> 3;          // 0..31
    int scol = (tid & 7) * 8;

    const TA* Abase = A + (size_t)blockM * lda;
    const short* Bbase = B + (size_t)blockN * ldb;

    // two named prefetch sets (rule #20: static, no runtime-indexed arrays)
    short8 a0_  = Ld8<TA>::load(Abase + (size_t)srow * lda + scol);
    short8 b00_ = Ld8<short>::load(Bbase + (size_t)srow * ldb + scol);
    short8 b10_ = Ld8<short>::load(Bbase + (size_t)(srow + 32) * ldb + scol);
    short8 a1_  = Ld8<TA>::load(Abase + (size_t)srow * lda + 64 + scol);
    short8 b01_ = Ld8<short>::load(Bbase + (size_t)srow * ldb + 64 + scol);
    short8 b11_ = Ld8<short>::load(Bbase + (size_t)(srow + 32) * ldb + 64 + scol);

    floatx4 acc[2];
    #pragma unroll
    for (int j = 0; j < 2; ++j)
        #pragma unroll
        for (int r = 0; r < 4; ++r) acc[j][r] = 0.f;

    int lane = tid & 63;
    int w = tid >> 6;
    int wr = w >> 1, wc = w & 1;   // wave: 16-row half x 32-col half
    int quad = lane >> 4, l15 = lane & 15;

    short* buf0 = lds;
    short* buf1 = lds + 96 * LDSTR;

    for (int it = 0; it < kTiles; it += 2) {
        // ---- even sub-iter: buf0 / set0 ----
        *(short8*)(buf0 + srow * LDSTR + scol) = a0_;
        *(short8*)(buf0 + (32 + srow) * LDSTR + scol) = b00_;
        *(short8*)(buf0 + (64 + srow) * LDSTR + scol) = b10_;
        asm volatile("s_waitcnt lgkmcnt(0)" ::: "memory");
        __builtin_amdgcn_s_barrier();
        if (it + 2 < kTiles) {
            int ko = (it + 2) * 64;
            a0_  = Ld8<TA>::load(Abase + (size_t)srow * lda + ko + scol);
            b00_ = Ld8<short>::load(Bbase + (size_t)srow * ldb + ko + scol);
            b10_ = Ld8<short>::load(Bbase + (size_t)(srow + 32) * ldb + ko + scol);
        }
        {
            const short* Arow = buf0 + (wr * 16 + l15) * LDSTR;
            const short* Brow = buf0 + (32 + wc * 32 + l15) * LDSTR;
            #pragma unroll
            for (int ks = 0; ks < 2; ++ks) {
                int kof = ks * 32 + quad * 8;
                short8 a0 = *(const short8*)(Arow + kof);
                short8 b0 = *(const short8*)(Brow + kof);
                short8 b1 = *(const short8*)(Brow + 16 * LDSTR + kof);
                acc[0] = __builtin_amdgcn_mfma_f32_16x16x32_bf16(a0, b0, acc[0], 0, 0, 0);
                acc[1] = __builtin_amdgcn_mfma_f32_16x16x32_bf16(a0, b1, acc[1], 0, 0, 0);
            }
        }
        // ---- odd sub-iter: buf1 / set1 ----
        *(short8*)(buf1 + srow * LDSTR + scol) = a1_;
        *(short8*)(buf1 + (32 + srow) * LDSTR + scol) = b01_;
        *(short8*)(buf1 + (64 + srow) * LDSTR + scol) = b11_;
        asm volatile("s_waitcnt lgkmcnt(0)" ::: "memory");
        __builtin_amdgcn_s_barrier();
        if (it + 3 < kTiles) {
            int ko = (it + 3) * 64;
            a1_  = Ld8<TA>::load(Abase + (size_t)srow * lda + ko + scol);
            b01_ = Ld8<short>::load(Bbase + (size_t)srow * ldb + ko + scol);
            b11_ = Ld8<short>::load(Bbase + (size_t)(srow + 32) * ldb + ko + scol);
        }
        {
            const short* Arow = buf1 + (wr * 16 + l15) * LDSTR;
            const short* Brow = buf1 + (32 + wc * 32 + l15) * LDSTR;
            #pragma unroll
            for (int ks = 0; ks < 2; ++ks) {
                int kof = ks * 32 + quad * 8;
                short8 a0 = *(const short8*)(Arow + kof);
                short8 b0 = *(const short8*)(Brow + kof);
                short8 b1 = *(const short8*)(Brow + 16 * LDSTR + kof);
                acc[0] = __builtin_amdgcn_mfma_f32_16x16x32_bf16(a0, b0, acc[0], 0, 0, 0);
                acc[1] = __builtin_amdgcn_mfma_f32_16x16x32_bf16(a0, b1, acc[1], 0, 0, 0);
            }
        }
    }

    #pragma unroll
    for (int tj = 0; tj < 2; ++tj) {
        int col = blockN + wc * 32 + tj * 16 + l15;
        float bv = bias[col];
        int m0 = blockM + wr * 16 + quad * 4;   // 4-aligned
        short4v pk;
        #pragma unroll
        for (int r = 0; r < 4; ++r) {
            int m = m0 + r;
            float xv = acc[tj][r] + bv;
            if (RELU) xv = xv > 0.f ? xv : 0.f;
            short v = to_bf16s(xv);
            pk[r] = v;
            int orow = ROWMAP ? (((m & 2047) << 2) | (m >> 11)) : m;
            C[(size_t)orow * ldc + col + colofs] = v;
            if (HTW && !ROWMAP) {
                // rows are n*4+b; b=m&3, n=m>>2
                HT[(size_t)((m & 3) * 128 + col) * 2048 + (m >> 2)] = v;
            }
        }
        if (HTW && ROWMAP) {
            // rows are b*2048+n; 4 consecutive n share b -> packed 8B store
            int b = m0 >> 11, n0 = m0 & 2047;
            *(short4v*)(HT + (size_t)(b * 128 + col) * 2048 + n0) = pk;
        }
    }
}

// ---------------------------------------------------------------------------
// gemmS: adjacency GEMM partials. 64x128 tile, BK=64 — R1's exact tiling and
// k-order — but DRAIN-FREE: 3-slot LDS (72KB), stage(it+2) via global_load_lds
// stays in flight across raw s_barriers; counted s_waitcnt vmcnt(6) (6 DMAs
// per staged iter; tail: vmcnt(0) at it==7 only). One barrier per iter.
// Correctness: a wave's vmcnt(6) bounds its own 12 outstanding DMAs to the
// newest 6 (= stage(it+1)), so stage(it) has landed; barrier publishes to all
// waves. slot (it+2)%3 was last read at compute(it-1), finished before
// barrier(it), and prior DMA writes to it landed (writer's vmcnt at it-1).
// A = adjS [2048][2048], B = HT [512][2048], K-chunk = blockIdx.z*512.
// Writes big[l][(m*4 + j>>7)*640 + (j&127) + z*128] (bf16) — z-partials summed
// implicitly by the next gemmT via the 4x-replicated Wr in BigB.
// grid (32,4,4) = 512 blocks, LDS 72KB -> 2 blocks/CU.
// ---------------------------------------------------------------------------
__global__ __launch_bounds__(256) void gemmS(const short* __restrict__ A,
                                             const short* __restrict__ B,
                                             short* __restrict__ C) {
    __shared__ __align__(16) short lds3[3 * 12288];  // per slot: As 4096 + Bs 8192

    int tid = threadIdx.x;
    int kz = blockIdx.z * 512;

    const short* Ab = A + (size_t)(blockIdx.x * 64 + (tid >> 3)) * 2048 + kz + (tid & 7) * 8;
    const short* Bb = B + (size_t)(blockIdx.y * 128 + (tid >> 3)) * 2048 + kz + (tid & 7) * 8;

    floatx4 acc[2][4];
    #pragma unroll
    for (int i = 0; i < 2; ++i)
        #pragma unroll
        for (int j = 0; j < 4; ++j)
            #pragma unroll
            for (int r = 0; r < 4; ++r) acc[i][j][r] = 0.f;

    int lane = tid & 63;
    int w = tid >> 6;
    int wr = w >> 1, wc = w & 1;   // wave: 32-row half x 64-col half
    int quad = lane >> 4, l15 = lane & 15;

    auto stage = [&](int slot, int it) {
        short* As = lds3 + slot * 12288;
        short* Bs = As + 4096;
        const short* Ag = Ab + it * 64;
        const short* Bg = Bb + it * 64;
        dma16(Ag, As + tid * 8);
        dma16(Ag + (size_t)32 * 2048, As + tid * 8 + 2048);
        #pragma unroll
        for (int r = 0; r < 4; ++r)
            dma16(Bg + (size_t)r * 32 * 2048, Bs + tid * 8 + r * 2048);
    };

    stage(0, 0);
    stage(1, 1);

    int slot = 0;
    for (int it = 0; it < 8; ++it) {
        if (it < 7) asm volatile("s_waitcnt vmcnt(6)" ::: "memory");
        else        asm volatile("s_waitcnt vmcnt(0)" ::: "memory");
        __builtin_amdgcn_s_barrier();   // raw: prefetch DMAs stay in flight
        if (it + 2 < 8) {
            int s2 = slot + 2; if (s2 >= 3) s2 -= 3;
            stage(s2, it + 2);
        }
        const short* As = lds3 + slot * 12288;
        const short* Ar = As + (wr * 32 + l15) * 64;
        const short* Br = As + 4096 + (wc * 64 + l15) * 64;
        #pragma unroll
        for (int ks = 0; ks < 2; ++ks) {
            int kof = ks * 32 + quad * 8;
            short8 af[2], bfr[4];
            #pragma unroll
            for (int i = 0; i < 2; ++i) af[i] = *(const short8*)(Ar + i * 16 * 64 + kof);
            #pragma unroll
            for (int j = 0; j < 4; ++j) bfr[j] = *(const short8*)(Br + j * 16 * 64 + kof);
            #pragma unroll
            for (int i = 0; i < 2; ++i)
                #pragma unroll
                for (int j = 0; j < 4; ++j)
                    acc[i][j] = __builtin_amdgcn_mfma_f32_16x16x32_bf16(af[i], bfr[j], acc[i][j], 0, 0, 0);
        }
        slot = (slot + 1 == 3) ? 0 : slot + 1;
    }

    int colofs = blockIdx.z * 128;
    #pragma unroll
    for (int ti = 0; ti < 2; ++ti) {
        #pragma unroll
        for (int tj = 0; tj < 4; ++tj) {
            int j = blockIdx.y * 128 + wc * 64 + tj * 16 + l15;  // 0..511 = b*128+d
            int jhi = j >> 7, jlo = j & 127;
            int row0 = blockIdx.x * 64 + wr * 32 + ti * 16 + quad * 4;
            #pragma unroll
            for (int r = 0; r < 4; ++r) {
                int m = row0 + r;  // node n
                C[(size_t)(m * 4 + jhi) * 640 + jlo + colofs] = to_bf16s(acc[ti][tj][r]);
            }
        }
    }
}

// ---------------------------------------------------------------------------
// gemm128: mlp1 (R1 verbatim). 128x128 tile, BK=64, global_load_lds 16B,
// 2-barrier loop (only 2 iters -> drain cost negligible).
// fp32 out, row (n*4+b) -> b*2048+n, +bias[col].
// ---------------------------------------------------------------------------
__global__ __launch_bounds__(256) void gemmL(
    const short* __restrict__ A, int lda,
    const short* __restrict__ B, int ldb,
    int kChunkIters, const float* __restrict__ bias,
    float* __restrict__ Cf, int ldc) {
    __shared__ __align__(16) short As[128 * 64];
    __shared__ __align__(16) short Bs[128 * 64];

    int tid = threadIdx.x;
    int blockM = blockIdx.x * 128;
    int blockN = blockIdx.y * 128;

    const short* Ab = A + (size_t)(blockM + (tid >> 3)) * lda + (tid & 7) * 8;
    const short* Bb = B + (size_t)(blockN + (tid >> 3)) * ldb + (tid & 7) * 8;
    short* Al = As + tid * 8;
    short* Bl = Bs + tid * 8;

    floatx4 acc[4][4];
    #pragma unroll
    for (int i = 0; i < 4; ++i)
        #pragma unroll
        for (int j = 0; j < 4; ++j)
            #pragma unroll
            for (int r = 0; r < 4; ++r) acc[i][j][r] = 0.f;

    int lane = tid & 63;
    int w = tid >> 6;
    int wr = w >> 1, wc = w & 1;
    int quad = lane >> 4, l15 = lane & 15;

    for (int it = 0; it < kChunkIters; ++it) {
        const short* Ag = Ab + it * 64;
        const short* Bg = Bb + it * 64;
        #pragma unroll
        for (int r = 0; r < 4; ++r) {
            dma16(Ag + (size_t)r * 32 * lda, Al + r * 2048);
            dma16(Bg + (size_t)r * 32 * ldb, Bl + r * 2048);
        }
        __syncthreads();
        const short* Ar = As + (wr * 64 + l15) * 64;
        const short* Br = Bs + (wc * 64 + l15) * 64;
        #pragma unroll
        for (int ks = 0; ks < 2; ++ks) {
            int kof = ks * 32 + quad * 8;
            short8 af[4], bfr[4];
            #pragma unroll
            for (int i = 0; i < 4; ++i) af[i] = *(const short8*)(Ar + i * 16 * 64 + kof);
            #pragma unroll
            for (int j = 0; j < 4; ++j) bfr[j] = *(const short8*)(Br + j * 16 * 64 + kof);
            #pragma unroll
            for (int i = 0; i < 4; ++i)
                #pragma unroll
                for (int j = 0; j < 4; ++j)
                    acc[i][j] = __builtin_amdgcn_mfma_f32_16x16x32_bf16(af[i], bfr[j], acc[i][j], 0, 0, 0);
        }
        __syncthreads();
    }

    #pragma unroll
    for (int ti = 0; ti < 4; ++ti) {
        #pragma unroll
        for (int tj = 0; tj < 4; ++tj) {
            int col = blockN + wc * 64 + tj * 16 + l15;
            float bv = bias[col];
            int row0 = blockM + wr * 64 + ti * 16 + quad * 4;
            #pragma unroll
            for (int r = 0; r < 4; ++r) {
                int mp = row0 + r;  // n*4+b
                int orow = ((mp & 3) << 11) | (mp >> 2);
                Cf[(size_t)orow * ldc + col] = acc[ti][tj][r] + bv;
            }
        }
    }
}

// ---------------------------------------------------------------------------
// Launch (identical structure to R1: 9 launches)
// ---------------------------------------------------------------------------
extern "C" void kernel_launch(void* const* d_in, const int* in_sizes, int n_in,
                              void* d_out, int out_size, void* d_ws, size_t ws_size,
                              hipStream_t stream) {
    const float* x      = (const float*)d_in[0];
    const float* adj    = (const float*)d_in[1];
    const float* W_mlp2 = (const float*)d_in[2];
    const float* b_mlp2 = (const float*)d_in[3];
    const float* Wr1    = (const float*)d_in[4];
    const float* Wo1    = (const float*)d_in[5];
    const float* b1     = (const float*)d_in[6];
    const float* Wr2    = (const float*)d_in[7];
    const float* Wo2    = (const float*)d_in[8];
    const float* b2     = (const float*)d_in[9];
    const float* Wr3    = (const float*)d_in[10];
    const float* Wo3    = (const float*)d_in[11];
    const float* b3     = (const float*)d_in[12];
    const float* W_mlp1 = (const float*)d_in[13];
    const float* b_mlp1 = (const float*)d_in[14];
    float* out = (float*)d_out;

    char* ws = (char*)d_ws;
    size_t off = 0;
    auto alloc = [&](size_t bytes) -> char* {
        char* p = ws + off;
        off = (off + bytes + 255) & ~(size_t)255;
        return p;
    };
    short* W2T  = (short*)alloc(128 * 1536 * 2);
    short* W1T  = (short*)alloc(1536 * 128 * 2);
    short* BigB[3];
    for (int l = 0; l < 3; ++l) BigB[l] = (short*)alloc(128 * 640 * 2);
    short* adjS = (short*)alloc((size_t)2048 * 2048 * 2);
    short* big[4];
    for (int l = 0; l < 4; ++l) big[l] = (short*)alloc((size_t)8192 * 640 * 2);
    short* HT = (short*)alloc((size_t)512 * 2048 * 2);

    dim3 blk(256);

    PrepArgs pa{adj, W_mlp2, W_mlp1, Wr1, Wo1, Wr2, Wo2, Wr3, Wo3,
                adjS, W2T, W1T, BigB[0], BigB[1], BigB[2]};
    prep<<<2528, blk, 0, stream>>>(pa);

    // mlp2: big0[n*4+b][512+d] = x[b*2048+n] @ W2 + b2, fused HT write
    // (M=8192, K=1536, N=128) grid (256,2) -> 2 blocks/CU
    gemmT<float, 0, 1, 1><<<dim3(256, 2), blk, 0, stream>>>(
        x, 1536, W2T, 1536, 24, b_mlp2, big[0], 640, 512, HT);

    for (int l = 0; l < 3; ++l) {
        // big_l[:,0:512] = adjS @ Hp_l partials in 4 K-chunks  (M=2048,N=512,K=2048)
        gemmS<<<dim3(32, 4, 4), blk, 0, stream>>>(adjS, HT, big[l]);
        // Hp_{l+1} = act(big_l @ BigB_l^T + b_l)  (M=8192,N=128,K=640), fused HT
        if (l == 0)
            gemmT<short, 1, 0, 1><<<dim3(256, 2), blk, 0, stream>>>(
                big[0], 640, BigB[0], 640, 10, b1, big[1], 640, 512, HT);
        else if (l == 1)
            gemmT<short, 1, 0, 1><<<dim3(256, 2), blk, 0, stream>>>(
                big[1], 640, BigB[1], 640, 10, b2, big[2], 640, 512, HT);
        else
            gemmT<short, 0, 0, 0><<<dim3(256, 2), blk, 0, stream>>>(
                big[2], 640, BigB[2], 640, 10, b3, big[3], 640, 512, nullptr);
    }

    // mlp1: out[b*2048+n] = Hp3 @ W1 + b1   (M=8192,N=1536,K=128)
    gemmL<<<dim3(64, 12), blk, 0, stream>>>(big[3] + 512, 640, W1T, 128, 2, b_mlp1, out, 1536);
}

// Round 7
// 212.479 us; speedup vs baseline: 1.1204x; 1.0349x over previous
//
#include <hip/hip_runtime.h>

typedef __attribute__((ext_vector_type(8))) short short8;
typedef __attribute__((ext_vector_type(4))) short short4v;
typedef __attribute__((ext_vector_type(4))) float floatx4;

// fp32 -> bf16 bits, round-to-nearest-even (finite inputs only)
__device__ inline short to_bf16s(float f) {
    unsigned u = __builtin_bit_cast(unsigned, f);
    unsigned r = u + 0x7FFFu + ((u >> 16) & 1u);
    return (short)(r >> 16);
}

// async 16B global -> LDS DMA (wave-uniform base + lane*16; lane-ordered layout)
__device__ inline void dma16(const short* g, short* l) {
    __builtin_amdgcn_global_load_lds(
        (const __attribute__((address_space(1))) unsigned int*)(const void*)g,
        (__attribute__((address_space(3))) unsigned int*)(void*)l,
        16, 0, 0);
}

// ---------------------------------------------------------------------------
// 8-element k-contiguous fragment loader -> bf16 bits
// ---------------------------------------------------------------------------
template <typename T> struct Ld8;
template <> struct Ld8<short> {
    static __device__ inline short8 load(const short* p) { return *(const short8*)p; }
};
template <> struct Ld8<float> {
    static __device__ inline short8 load(const float* p) {
        float4 f0 = *(const float4*)p;
        float4 f1 = *(const float4*)(p + 4);
        short8 r;
        r[0] = to_bf16s(f0.x); r[1] = to_bf16s(f0.y);
        r[2] = to_bf16s(f0.z); r[3] = to_bf16s(f0.w);
        r[4] = to_bf16s(f1.x); r[5] = to_bf16s(f1.y);
        r[6] = to_bf16s(f1.z); r[7] = to_bf16s(f1.w);
        return r;
    }
};

// ---------------------------------------------------------------------------
// prep: blocks [0,2048): adjS[row] = adj[row] * (1/max(rowsum,1)), fp32->bf16.
//       blocks [2048,2528): weight transposes into W2T, W1T, BigB[3].
// BigB_l [128][640]: cols kc*128+k = Wr_l[k][j] (kc=0..3), cols 512+k = Wo_l[k][j].
// (unchanged — summation order preserved so absmax stays bit-identical)
// ---------------------------------------------------------------------------
struct PrepArgs {
    const float* adj;
    const float* W2; const float* W1;
    const float* Wr0; const float* Wo0;
    const float* Wr1; const float* Wo1;
    const float* Wr2; const float* Wo2;
    short* adjS; short* W2T; short* W1T;
    short* BigB0; short* BigB1; short* BigB2;
};

__global__ __launch_bounds__(256) void prep(PrepArgs p) {
    int bid = blockIdx.x;
    if (bid < 2048) {
        const float* src = p.adj + (size_t)bid * 2048;
        float s = 0.f;
        for (int c = threadIdx.x; c < 2048; c += 256) s += src[c];
        __shared__ float red[256];
        red[threadIdx.x] = s;
        __syncthreads();
        for (int st = 128; st > 0; st >>= 1) {
            if (threadIdx.x < st) red[threadIdx.x] += red[threadIdx.x + st];
            __syncthreads();
        }
        float d = red[0];
        d = d < 1.f ? 1.f : d;
        float inv = 1.f / d;
        short* dst = p.adjS + (size_t)bid * 2048;
        for (int c = threadIdx.x; c < 2048; c += 256) dst[c] = to_bf16s(src[c] * inv);
        return;
    }
    int t = bid - 2048;
    __shared__ short tile[32][33];
    int tx = threadIdx.x & 31, ty0 = threadIdx.x >> 5;
    const float* in; int C_; int bx, by;
    short* outp; int outld, copies, copystride, outofs;
    if (t < 192) {  // W2 [1536][128] -> W2T [128][1536]
        bx = (t & 3) * 32; by = (t >> 2) * 32; in = p.W2; C_ = 128;
        outp = p.W2T; outld = 1536; copies = 1; copystride = 0; outofs = 0;
    } else if (t < 384) {  // W1 [128][1536] -> W1T [1536][128]
        int u = t - 192; bx = (u % 48) * 32; by = (u / 48) * 32; in = p.W1; C_ = 1536;
        outp = p.W1T; outld = 128; copies = 1; copystride = 0; outofs = 0;
    } else {  // Wr/Wo [128][128] -> BigB_l
        int u = t - 384; int l = u / 32; int v = u % 32;
        const float* Wr[3] = {p.Wr0, p.Wr1, p.Wr2};
        const float* Wo[3] = {p.Wo0, p.Wo1, p.Wo2};
        short* BB[3] = {p.BigB0, p.BigB1, p.BigB2};
        outp = BB[l]; outld = 640; C_ = 128;
        if (v < 16) { in = Wr[l]; bx = (v & 3) * 32; by = (v >> 2) * 32;
                      copies = 4; copystride = 128; outofs = 0; }
        else { v -= 16; in = Wo[l]; bx = (v & 3) * 32; by = (v >> 2) * 32;
               copies = 1; copystride = 0; outofs = 512; }
    }
    for (int i = ty0; i < 32; i += 8)
        tile[i][tx] = to_bf16s(in[(size_t)(by + i) * C_ + bx + tx]);
    __syncthreads();
    for (int i = ty0; i < 32; i += 8) {
        short v = tile[tx][i];
        for (int c = 0; c < copies; ++c)
            outp[(size_t)(bx + i) * outld + (by + tx) + outofs + c * copystride] = v;
    }
}

#define LDSTR 72

// ---------------------------------------------------------------------------
// gemmT: C = A[M,K] @ B[N,K]^T, 32x64 tile, BK=64. DRAIN-FREE pipeline
// (R6 verbatim): 2-deep reg prefetch, raw s_barrier + lgkmcnt(0) only,
// dbuf LDS, one barrier/iter. LDSTR=72 pad -> bank-optimal ds_reads
// (stride 144B ≡ 4 banks mod 32; verified 8 accesses/bank).
// Epilogue: +bias, optional relu, optional rowmap, colofs, bf16 out.
// rowmap=1: row m=b*2048+n -> orow n*4+b.
// HTW: also write HT[(b*128+col)*2048 + n] directly from registers.
// ---------------------------------------------------------------------------
template <typename TA, int RELU, int ROWMAP, int HTW>
__global__ __launch_bounds__(256) void gemmT(
    const TA* __restrict__ A, int lda,
    const short* __restrict__ B, int ldb, int kTiles,
    const float* __restrict__ bias,
    short* __restrict__ C, int ldc, int colofs,
    short* __restrict__ HT) {
    __shared__ __align__(16) short lds[2 * 96 * LDSTR];

    int tid = threadIdx.x;
    int blockM = blockIdx.x * 32;
    int blockN = blockIdx.y * 64;

    int srow = tid >> 3;          // 0..31
    int scol = (tid & 7) * 8;

    const TA* Abase = A + (size_t)blockM * lda;
    const short* Bbase = B + (size_t)blockN * ldb;

    // two named prefetch sets (rule #20: static, no runtime-indexed arrays)
    short8 a0_  = Ld8<TA>::load(Abase + (size_t)srow * lda + scol);
    short8 b00_ = Ld8<short>::load(Bbase + (size_t)srow * ldb + scol);
    short8 b10_ = Ld8<short>::load(Bbase + (size_t)(srow + 32) * ldb + scol);
    short8 a1_  = Ld8<TA>::load(Abase + (size_t)srow * lda + 64 + scol);
    short8 b01_ = Ld8<short>::load(Bbase + (size_t)srow * ldb + 64 + scol);
    short8 b11_ = Ld8<short>::load(Bbase + (size_t)(srow + 32) * ldb + 64 + scol);

    floatx4 acc[2];
    #pragma unroll
    for (int j = 0; j < 2; ++j)
        #pragma unroll
        for (int r = 0; r < 4; ++r) acc[j][r] = 0.f;

    int lane = tid & 63;
    int w = tid >> 6;
    int wr = w >> 1, wc = w & 1;   // wave: 16-row half x 32-col half
    int quad = lane >> 4, l15 = lane & 15;

    short* buf0 = lds;
    short* buf1 = lds + 96 * LDSTR;

    for (int it = 0; it < kTiles; it += 2) {
        // ---- even sub-iter: buf0 / set0 ----
        *(short8*)(buf0 + srow * LDSTR + scol) = a0_;
        *(short8*)(buf0 + (32 + srow) * LDSTR + scol) = b00_;
        *(short8*)(buf0 + (64 + srow) * LDSTR + scol) = b10_;
        asm volatile("s_waitcnt lgkmcnt(0)" ::: "memory");
        __builtin_amdgcn_s_barrier();
        if (it + 2 < kTiles) {
            int ko = (it + 2) * 64;
            a0_  = Ld8<TA>::load(Abase + (size_t)srow * lda + ko + scol);
            b00_ = Ld8<short>::load(Bbase + (size_t)srow * ldb + ko + scol);
            b10_ = Ld8<short>::load(Bbase + (size_t)(srow + 32) * ldb + ko + scol);
        }
        {
            const short* Arow = buf0 + (wr * 16 + l15) * LDSTR;
            const short* Brow = buf0 + (32 + wc * 32 + l15) * LDSTR;
            #pragma unroll
            for (int ks = 0; ks < 2; ++ks) {
                int kof = ks * 32 + quad * 8;
                short8 a0 = *(const short8*)(Arow + kof);
                short8 b0 = *(const short8*)(Brow + kof);
                short8 b1 = *(const short8*)(Brow + 16 * LDSTR + kof);
                acc[0] = __builtin_amdgcn_mfma_f32_16x16x32_bf16(a0, b0, acc[0], 0, 0, 0);
                acc[1] = __builtin_amdgcn_mfma_f32_16x16x32_bf16(a0, b1, acc[1], 0, 0, 0);
            }
        }
        // ---- odd sub-iter: buf1 / set1 ----
        *(short8*)(buf1 + srow * LDSTR + scol) = a1_;
        *(short8*)(buf1 + (32 + srow) * LDSTR + scol) = b01_;
        *(short8*)(buf1 + (64 + srow) * LDSTR + scol) = b11_;
        asm volatile("s_waitcnt lgkmcnt(0)" ::: "memory");
        __builtin_amdgcn_s_barrier();
        if (it + 3 < kTiles) {
            int ko = (it + 3) * 64;
            a1_  = Ld8<TA>::load(Abase + (size_t)srow * lda + ko + scol);
            b01_ = Ld8<short>::load(Bbase + (size_t)srow * ldb + ko + scol);
            b11_ = Ld8<short>::load(Bbase + (size_t)(srow + 32) * ldb + ko + scol);
        }
        {
            const short* Arow = buf1 + (wr * 16 + l15) * LDSTR;
            const short* Brow = buf1 + (32 + wc * 32 + l15) * LDSTR;
            #pragma unroll
            for (int ks = 0; ks < 2; ++ks) {
                int kof = ks * 32 + quad * 8;
                short8 a0 = *(const short8*)(Arow + kof);
                short8 b0 = *(const short8*)(Brow + kof);
                short8 b1 = *(const short8*)(Brow + 16 * LDSTR + kof);
                acc[0] = __builtin_amdgcn_mfma_f32_16x16x32_bf16(a0, b0, acc[0], 0, 0, 0);
                acc[1] = __builtin_amdgcn_mfma_f32_16x16x32_bf16(a0, b1, acc[1], 0, 0, 0);
            }
        }
    }

    #pragma unroll
    for (int tj = 0; tj < 2; ++tj) {
        int col = blockN + wc * 32 + tj * 16 + l15;
        float bv = bias[col];
        int m0 = blockM + wr * 16 + quad * 4;   // 4-aligned
        short4v pk;
        #pragma unroll
        for (int r = 0; r < 4; ++r) {
            int m = m0 + r;
            float xv = acc[tj][r] + bv;
            if (RELU) xv = xv > 0.f ? xv : 0.f;
            short v = to_bf16s(xv);
            pk[r] = v;
            int orow = ROWMAP ? (((m & 2047) << 2) | (m >> 11)) : m;
            C[(size_t)orow * ldc + col + colofs] = v;
            if (HTW && !ROWMAP) {
                // rows are n*4+b; b=m&3, n=m>>2
                HT[(size_t)((m & 3) * 128 + col) * 2048 + (m >> 2)] = v;
            }
        }
        if (HTW && ROWMAP) {
            // rows are b*2048+n; 4 consecutive n share b -> packed 8B store
            int b = m0 >> 11, n0 = m0 & 2047;
            *(short4v*)(HT + (size_t)(b * 128 + col) * 2048 + n0) = pk;
        }
    }
}

// ---------------------------------------------------------------------------
// gemmS: adjacency GEMM partials. R6 drain-free 3-slot structure, PLUS
// T2 XOR-SWIZZLE (both-sides, rule #21): the 64-short (=128B = 32-bank) LDS
// rows made every wave-wide ds_read_b128 hit only 16 banks at 16 accesses
// each (2x the 8/bank optimum). Fix: LDS dest stays linear (dma16 law);
// the per-lane GLOBAL source col-group is pre-swizzled (t&7)^((t>>3)&7),
// and the read applies the same XOR: col-group (ks*4+quad)^(l15&7).
// Permutations compose to identity -> bit-identical MFMA inputs; banks now
// 8 accesses across all 32 (optimal). Everything else identical to R6.
// ---------------------------------------------------------------------------
__global__ __launch_bounds__(256) void gemmS(const short* __restrict__ A,
                                             const short* __restrict__ B,
                                             short* __restrict__ C) {
    __shared__ __align__(16) short lds3[3 * 12288];  // per slot: As 4096 + Bs 8192

    int tid = threadIdx.x;
    int kz = blockIdx.z * 512;

    // pre-swizzled global source col-group (T2 write side)
    int kswz = (((tid & 7) ^ ((tid >> 3) & 7))) * 8;
    const short* Ab = A + (size_t)(blockIdx.x * 64 + (tid >> 3)) * 2048 + kz + kswz;
    const short* Bb = B + (size_t)(blockIdx.y * 128 + (tid >> 3)) * 2048 + kz + kswz;

    floatx4 acc[2][4];
    #pragma unroll
    for (int i = 0; i < 2; ++i)
        #pragma unroll
        for (int j = 0; j < 4; ++j)
            #pragma unroll
            for (int r = 0; r < 4; ++r) acc[i][j][r] = 0.f;

    int lane = tid & 63;
    int w = tid >> 6;
    int wr = w >> 1, wc = w & 1;   // wave: 32-row half x 64-col half
    int quad = lane >> 4, l15 = lane & 15;

    auto stage = [&](int slot, int it) {
        short* As = lds3 + slot * 12288;
        short* Bs = As + 4096;
        const short* Ag = Ab + it * 64;
        const short* Bg = Bb + it * 64;
        dma16(Ag, As + tid * 8);
        dma16(Ag + (size_t)32 * 2048, As + tid * 8 + 2048);
        #pragma unroll
        for (int r = 0; r < 4; ++r)
            dma16(Bg + (size_t)r * 32 * 2048, Bs + tid * 8 + r * 2048);
    };

    stage(0, 0);
    stage(1, 1);

    int slot = 0;
    for (int it = 0; it < 8; ++it) {
        if (it < 7) asm volatile("s_waitcnt vmcnt(6)" ::: "memory");
        else        asm volatile("s_waitcnt vmcnt(0)" ::: "memory");
        __builtin_amdgcn_s_barrier();   // raw: prefetch DMAs stay in flight
        if (it + 2 < 8) {
            int s2 = slot + 2; if (s2 >= 3) s2 -= 3;
            stage(s2, it + 2);
        }
        const short* As = lds3 + slot * 12288;
        const short* Bs = As + 4096;
        #pragma unroll
        for (int ks = 0; ks < 2; ++ks) {
            // swizzled read col-group (T2 read side): identity vs global data
            int cswz = (((ks * 4 + quad) ^ (l15 & 7))) * 8;
            short8 af[2], bfr[4];
            #pragma unroll
            for (int i = 0; i < 2; ++i)
                af[i] = *(const short8*)(As + (wr * 32 + i * 16 + l15) * 64 + cswz);
            #pragma unroll
            for (int j = 0; j < 4; ++j)
                bfr[j] = *(const short8*)(Bs + (wc * 64 + j * 16 + l15) * 64 + cswz);
            #pragma unroll
            for (int i = 0; i < 2; ++i)
                #pragma unroll
                for (int j = 0; j < 4; ++j)
                    acc[i][j] = __builtin_amdgcn_mfma_f32_16x16x32_bf16(af[i], bfr[j], acc[i][j], 0, 0, 0);
        }
        slot = (slot + 1 == 3) ? 0 : slot + 1;
    }

    int colofs = blockIdx.z * 128;
    #pragma unroll
    for (int ti = 0; ti < 2; ++ti) {
        #pragma unroll
        for (int tj = 0; tj < 4; ++tj) {
            int j = blockIdx.y * 128 + wc * 64 + tj * 16 + l15;  // 0..511 = b*128+d
            int jhi = j >> 7, jlo = j & 127;
            int row0 = blockIdx.x * 64 + wr * 32 + ti * 16 + quad * 4;
            #pragma unroll
            for (int r = 0; r < 4; ++r) {
                int m = row0 + r;  // node n
                C[(size_t)(m * 4 + jhi) * 640 + jlo + colofs] = to_bf16s(acc[ti][tj][r]);
            }
        }
    }
}

// ---------------------------------------------------------------------------
// gemmL: mlp1. R6 structure (128x128 tile, BK=64, dma16, 2-barrier loop,
// 2 iters) PLUS the same T2 XOR-swizzle as gemmS (64-short rows were
// 2x bank-conflicted). fp32 out, row (n*4+b) -> b*2048+n, +bias[col].
// ---------------------------------------------------------------------------
__global__ __launch_bounds__(256) void gemmL(
    const short* __restrict__ A, int lda,
    const short* __restrict__ B, int ldb,
    int kChunkIters, const float* __restrict__ bias,
    float* __restrict__ Cf, int ldc) {
    __shared__ __align__(16) short As[128 * 64];
    __shared__ __align__(16) short Bs[128 * 64];

    int tid = threadIdx.x;
    int blockM = blockIdx.x * 128;
    int blockN = blockIdx.y * 128;

    // pre-swizzled global source col-group (T2 write side)
    int kswz = (((tid & 7) ^ ((tid >> 3) & 7))) * 8;
    const short* Ab = A + (size_t)(blockM + (tid >> 3)) * lda + kswz;
    const short* Bb = B + (size_t)(blockN + (tid >> 3)) * ldb + kswz;
    short* Al = As + tid * 8;
    short* Bl = Bs + tid * 8;

    floatx4 acc[4][4];
    #pragma unroll
    for (int i = 0; i < 4; ++i)
        #pragma unroll
        for (int j = 0; j < 4; ++j)
            #pragma unroll
            for (int r = 0; r < 4; ++r) acc[i][j][r] = 0.f;

    int lane = tid & 63;
    int w = tid >> 6;
    int wr = w >> 1, wc = w & 1;
    int quad = lane >> 4, l15 = lane & 15;

    for (int it = 0; it < kChunkIters; ++it) {
        const short* Ag = Ab + it * 64;
        const short* Bg = Bb + it * 64;
        #pragma unroll
        for (int r = 0; r < 4; ++r) {
            dma16(Ag + (size_t)r * 32 * lda, Al + r * 2048);
            dma16(Bg + (size_t)r * 32 * ldb, Bl + r * 2048);
        }
        __syncthreads();
        #pragma unroll
        for (int ks = 0; ks < 2; ++ks) {
            // swizzled read col-group (T2 read side)
            int cswz = (((ks * 4 + quad) ^ (l15 & 7))) * 8;
            short8 af[4], bfr[4];
            #pragma unroll
            for (int i = 0; i < 4; ++i)
                af[i] = *(const short8*)(As + (wr * 64 + i * 16 + l15) * 64 + cswz);
            #pragma unroll
            for (int j = 0; j < 4; ++j)
                bfr[j] = *(const short8*)(Bs + (wc * 64 + j * 16 + l15) * 64 + cswz);
            #pragma unroll
            for (int i = 0; i < 4; ++i)
                #pragma unroll
                for (int j = 0; j < 4; ++j)
                    acc[i][j] = __builtin_amdgcn_mfma_f32_16x16x32_bf16(af[i], bfr[j], acc[i][j], 0, 0, 0);
        }
        __syncthreads();
    }

    #pragma unroll
    for (int ti = 0; ti < 4; ++ti) {
        #pragma unroll
        for (int tj = 0; tj < 4; ++tj) {
            int col = blockN + wc * 64 + tj * 16 + l15;
            float bv = bias[col];
            int row0 = blockM + wr * 64 + ti * 16 + quad * 4;
            #pragma unroll
            for (int r = 0; r < 4; ++r) {
                int mp = row0 + r;  // n*4+b
                int orow = ((mp & 3) << 11) | (mp >> 2);
                Cf[(size_t)orow * ldc + col] = acc[ti][tj][r] + bv;
            }
        }
    }
}

// ---------------------------------------------------------------------------
// Launch (identical structure to R6: 9 launches)
// ---------------------------------------------------------------------------
extern "C" void kernel_launch(void* const* d_in, const int* in_sizes, int n_in,
                              void* d_out, int out_size, void* d_ws, size_t ws_size,
                              hipStream_t stream) {
    const float* x      = (const float*)d_in[0];
    const float* adj    = (const float*)d_in[1];
    const float* W_mlp2 = (const float*)d_in[2];
    const float* b_mlp2 = (const float*)d_in[3];
    const float* Wr1    = (const float*)d_in[4];
    const float* Wo1    = (const float*)d_in[5];
    const float* b1     = (const float*)d_in[6];
    const float* Wr2    = (const float*)d_in[7];
    const float* Wo2    = (const float*)d_in[8];
    const float* b2     = (const float*)d_in[9];
    const float* Wr3    = (const float*)d_in[10];
    const float* Wo3    = (const float*)d_in[11];
    const float* b3     = (const float*)d_in[12];
    const float* W_mlp1 = (const float*)d_in[13];
    const float* b_mlp1 = (const float*)d_in[14];
    float* out = (float*)d_out;

    char* ws = (char*)d_ws;
    size_t off = 0;
    auto alloc = [&](size_t bytes) -> char* {
        char* p = ws + off;
        off = (off + bytes + 255) & ~(size_t)255;
        return p;
    };
    short* W2T  = (short*)alloc(128 * 1536 * 2);
    short* W1T  = (short*)alloc(1536 * 128 * 2);
    short* BigB[3];
    for (int l = 0; l < 3; ++l) BigB[l] = (short*)alloc(128 * 640 * 2);
    short* adjS = (short*)alloc((size_t)2048 * 2048 * 2);
    short* big[4];
    for (int l = 0; l < 4; ++l) big[l] = (short*)alloc((size_t)8192 * 640 * 2);
    short* HT = (short*)alloc((size_t)512 * 2048 * 2);

    dim3 blk(256);

    PrepArgs pa{adj, W_mlp2, W_mlp1, Wr1, Wo1, Wr2, Wo2, Wr3, Wo3,
                adjS, W2T, W1T, BigB[0], BigB[1], BigB[2]};
    prep<<<2528, blk, 0, stream>>>(pa);

    // mlp2: big0[n*4+b][512+d] = x[b*2048+n] @ W2 + b2, fused HT write
    // (M=8192, K=1536, N=128) grid (256,2) -> 2 blocks/CU
    gemmT<float, 0, 1, 1><<<dim3(256, 2), blk, 0, stream>>>(
        x, 1536, W2T, 1536, 24, b_mlp2, big[0], 640, 512, HT);

    for (int l = 0; l < 3; ++l) {
        // big_l[:,0:512] = adjS @ Hp_l partials in 4 K-chunks  (M=2048,N=512,K=2048)
        gemmS<<<dim3(32, 4, 4), blk, 0, stream>>>(adjS, HT, big[l]);
        // Hp_{l+1} = act(big_l @ BigB_l^T + b_l)  (M=8192,N=128,K=640), fused HT
        if (l == 0)
            gemmT<short, 1, 0, 1><<<dim3(256, 2), blk, 0, stream>>>(
                big[0], 640, BigB[0], 640, 10, b1, big[1], 640, 512, HT);
        else if (l == 1)
            gemmT<short, 1, 0, 1><<<dim3(256, 2), blk, 0, stream>>>(
                big[1], 640, BigB[1], 640, 10, b2, big[2], 640, 512, HT);
        else
            gemmT<short, 0, 0, 0><<<dim3(256, 2), blk, 0, stream>>>(
                big[2], 640, BigB[2], 640, 10, b3, big[3], 640, 512, nullptr);
    }

    // mlp1: out[b*2048+n] = Hp3 @ W1 + b1   (M=8192,N=1536,K=128)
    gemmL<<<dim3(64, 12), blk, 0, stream>>>(big[3] + 512, 640, W1T, 128, 2, b_mlp1, out, 1536);
}

// Round 8
// 211.738 us; speedup vs baseline: 1.1243x; 1.0035x over previous
//
#include <hip/hip_runtime.h>

typedef __attribute__((ext_vector_type(8))) short short8;
typedef __attribute__((ext_vector_type(4))) short short4v;
typedef __attribute__((ext_vector_type(4))) float floatx4;

// fp32 -> bf16 bits, round-to-nearest-even (finite inputs only)
__device__ inline short to_bf16s(float f) {
    unsigned u = __builtin_bit_cast(unsigned, f);
    unsigned r = u + 0x7FFFu + ((u >> 16) & 1u);
    return (short)(r >> 16);
}

// async 16B global -> LDS DMA (wave-uniform base + lane*16; lane-ordered layout)
__device__ inline void dma16(const short* g, short* l) {
    __builtin_amdgcn_global_load_lds(
        (const __attribute__((address_space(1))) unsigned int*)(const void*)g,
        (__attribute__((address_space(3))) unsigned int*)(void*)l,
        16, 0, 0);
}

// ---------------------------------------------------------------------------
// 8-element k-contiguous fragment loader -> bf16 bits
// ---------------------------------------------------------------------------
template <typename T> struct Ld8;
template <> struct Ld8<short> {
    static __device__ inline short8 load(const short* p) { return *(const short8*)p; }
};
template <> struct Ld8<float> {
    static __device__ inline short8 load(const float* p) {
        float4 f0 = *(const float4*)p;
        float4 f1 = *(const float4*)(p + 4);
        short8 r;
        r[0] = to_bf16s(f0.x); r[1] = to_bf16s(f0.y);
        r[2] = to_bf16s(f0.z); r[3] = to_bf16s(f0.w);
        r[4] = to_bf16s(f1.x); r[5] = to_bf16s(f1.y);
        r[6] = to_bf16s(f1.z); r[7] = to_bf16s(f1.w);
        return r;
    }
};

// ---------------------------------------------------------------------------
// prepW: weight transposes only (480 blocks). Same math as R7's prep tail.
// BigB_l [128][640]: cols kc*128+k = Wr_l[k][j] (kc=0..3), cols 512+k = Wo_l[k][j].
// ---------------------------------------------------------------------------
struct PrepArgs {
    const float* adj;
    const float* W2; const float* W1;
    const float* Wr0; const float* Wo0;
    const float* Wr1; const float* Wo1;
    const float* Wr2; const float* Wo2;
    short* adjS; short* W2T; short* W1T;
    short* BigB0; short* BigB1; short* BigB2;
};

__global__ __launch_bounds__(256) void prepW(PrepArgs p) {
    int t = blockIdx.x;
    __shared__ short tile[32][33];
    int tx = threadIdx.x & 31, ty0 = threadIdx.x >> 5;
    const float* in; int C_; int bx, by;
    short* outp; int outld, copies, copystride, outofs;
    if (t < 192) {  // W2 [1536][128] -> W2T [128][1536]
        bx = (t & 3) * 32; by = (t >> 2) * 32; in = p.W2; C_ = 128;
        outp = p.W2T; outld = 1536; copies = 1; copystride = 0; outofs = 0;
    } else if (t < 384) {  // W1 [128][1536] -> W1T [1536][128]
        int u = t - 192; bx = (u % 48) * 32; by = (u / 48) * 32; in = p.W1; C_ = 1536;
        outp = p.W1T; outld = 128; copies = 1; copystride = 0; outofs = 0;
    } else {  // Wr/Wo [128][128] -> BigB_l
        int u = t - 384; int l = u / 32; int v = u % 32;
        const float* Wr[3] = {p.Wr0, p.Wr1, p.Wr2};
        const float* Wo[3] = {p.Wo0, p.Wo1, p.Wo2};
        short* BB[3] = {p.BigB0, p.BigB1, p.BigB2};
        outp = BB[l]; outld = 640; C_ = 128;
        if (v < 16) { in = Wr[l]; bx = (v & 3) * 32; by = (v >> 2) * 32;
                      copies = 4; copystride = 128; outofs = 0; }
        else { v -= 16; in = Wo[l]; bx = (v & 3) * 32; by = (v >> 2) * 32;
               copies = 1; copystride = 0; outofs = 512; }
    }
    for (int i = ty0; i < 32; i += 8)
        tile[i][tx] = to_bf16s(in[(size_t)(by + i) * C_ + bx + tx]);
    __syncthreads();
    for (int i = ty0; i < 32; i += 8) {
        short v = tile[tx][i];
        for (int c = 0; c < copies; ++c)
            outp[(size_t)(bx + i) * outld + (by + tx) + outofs + c * copystride] = v;
    }
}

#define LDSTR 72

// ---------------------------------------------------------------------------
// dev_gemmT: C = A[M,K] @ B[N,K]^T, 32x64 tile, BK=64. R7 drain-free body
// verbatim as a device function (2-deep named reg prefetch, raw s_barrier +
// lgkmcnt(0) only, dbuf LDS, one barrier/iter, LDSTR=72 bank-safe pad).
// ---------------------------------------------------------------------------
template <typename TA, int RELU, int ROWMAP, int HTW>
__device__ __forceinline__ void dev_gemmT(
    short* lds, int bidx, int bidy,
    const TA* __restrict__ A, int lda,
    const short* __restrict__ B, int ldb, int kTiles,
    const float* __restrict__ bias,
    short* __restrict__ C, int ldc, int colofs,
    short* __restrict__ HT) {
    int tid = threadIdx.x;
    int blockM = bidx * 32;
    int blockN = bidy * 64;

    int srow = tid >> 3;          // 0..31
    int scol = (tid & 7) * 8;

    const TA* Abase = A + (size_t)blockM * lda;
    const short* Bbase = B + (size_t)blockN * ldb;

    // two named prefetch sets (rule #20: static, no runtime-indexed arrays)
    short8 a0_  = Ld8<TA>::load(Abase + (size_t)srow * lda + scol);
    short8 b00_ = Ld8<short>::load(Bbase + (size_t)srow * ldb + scol);
    short8 b10_ = Ld8<short>::load(Bbase + (size_t)(srow + 32) * ldb + scol);
    short8 a1_  = Ld8<TA>::load(Abase + (size_t)srow * lda + 64 + scol);
    short8 b01_ = Ld8<short>::load(Bbase + (size_t)srow * ldb + 64 + scol);
    short8 b11_ = Ld8<short>::load(Bbase + (size_t)(srow + 32) * ldb + 64 + scol);

    floatx4 acc[2];
    #pragma unroll
    for (int j = 0; j < 2; ++j)
        #pragma unroll
        for (int r = 0; r < 4; ++r) acc[j][r] = 0.f;

    int lane = tid & 63;
    int w = tid >> 6;
    int wr = w >> 1, wc = w & 1;   // wave: 16-row half x 32-col half
    int quad = lane >> 4, l15 = lane & 15;

    short* buf0 = lds;
    short* buf1 = lds + 96 * LDSTR;

    for (int it = 0; it < kTiles; it += 2) {
        // ---- even sub-iter: buf0 / set0 ----
        *(short8*)(buf0 + srow * LDSTR + scol) = a0_;
        *(short8*)(buf0 + (32 + srow) * LDSTR + scol) = b00_;
        *(short8*)(buf0 + (64 + srow) * LDSTR + scol) = b10_;
        asm volatile("s_waitcnt lgkmcnt(0)" ::: "memory");
        __builtin_amdgcn_s_barrier();
        if (it + 2 < kTiles) {
            int ko = (it + 2) * 64;
            a0_  = Ld8<TA>::load(Abase + (size_t)srow * lda + ko + scol);
            b00_ = Ld8<short>::load(Bbase + (size_t)srow * ldb + ko + scol);
            b10_ = Ld8<short>::load(Bbase + (size_t)(srow + 32) * ldb + ko + scol);
        }
        {
            const short* Arow = buf0 + (wr * 16 + l15) * LDSTR;
            const short* Brow = buf0 + (32 + wc * 32 + l15) * LDSTR;
            #pragma unroll
            for (int ks = 0; ks < 2; ++ks) {
                int kof = ks * 32 + quad * 8;
                short8 a0 = *(const short8*)(Arow + kof);
                short8 b0 = *(const short8*)(Brow + kof);
                short8 b1 = *(const short8*)(Brow + 16 * LDSTR + kof);
                acc[0] = __builtin_amdgcn_mfma_f32_16x16x32_bf16(a0, b0, acc[0], 0, 0, 0);
                acc[1] = __builtin_amdgcn_mfma_f32_16x16x32_bf16(a0, b1, acc[1], 0, 0, 0);
            }
        }
        // ---- odd sub-iter: buf1 / set1 ----
        *(short8*)(buf1 + srow * LDSTR + scol) = a1_;
        *(short8*)(buf1 + (32 + srow) * LDSTR + scol) = b01_;
        *(short8*)(buf1 + (64 + srow) * LDSTR + scol) = b11_;
        asm volatile("s_waitcnt lgkmcnt(0)" ::: "memory");
        __builtin_amdgcn_s_barrier();
        if (it + 3 < kTiles) {
            int ko = (it + 3) * 64;
            a1_  = Ld8<TA>::load(Abase + (size_t)srow * lda + ko + scol);
            b01_ = Ld8<short>::load(Bbase + (size_t)srow * ldb + ko + scol);
            b11_ = Ld8<short>::load(Bbase + (size_t)(srow + 32) * ldb + ko + scol);
        }
        {
            const short* Arow = buf1 + (wr * 16 + l15) * LDSTR;
            const short* Brow = buf1 + (32 + wc * 32 + l15) * LDSTR;
            #pragma unroll
            for (int ks = 0; ks < 2; ++ks) {
                int kof = ks * 32 + quad * 8;
                short8 a0 = *(const short8*)(Arow + kof);
                short8 b0 = *(const short8*)(Brow + kof);
                short8 b1 = *(const short8*)(Brow + 16 * LDSTR + kof);
                acc[0] = __builtin_amdgcn_mfma_f32_16x16x32_bf16(a0, b0, acc[0], 0, 0, 0);
                acc[1] = __builtin_amdgcn_mfma_f32_16x16x32_bf16(a0, b1, acc[1], 0, 0, 0);
            }
        }
    }

    #pragma unroll
    for (int tj = 0; tj < 2; ++tj) {
        int col = blockN + wc * 32 + tj * 16 + l15;
        float bv = bias[col];
        int m0 = blockM + wr * 16 + quad * 4;   // 4-aligned
        short4v pk;
        #pragma unroll
        for (int r = 0; r < 4; ++r) {
            int m = m0 + r;
            float xv = acc[tj][r] + bv;
            if (RELU) xv = xv > 0.f ? xv : 0.f;
            short v = to_bf16s(xv);
            pk[r] = v;
            int orow = ROWMAP ? (((m & 2047) << 2) | (m >> 11)) : m;
            C[(size_t)orow * ldc + col + colofs] = v;
            if (HTW && !ROWMAP) {
                // rows are n*4+b; b=m&3, n=m>>2
                HT[(size_t)((m & 3) * 128 + col) * 2048 + (m >> 2)] = v;
            }
        }
        if (HTW && ROWMAP) {
            // rows are b*2048+n; 4 consecutive n share b -> packed 8B store
            int b = m0 >> 11, n0 = m0 & 2047;
            *(short4v*)(HT + (size_t)(b * 128 + col) * 2048 + n0) = pk;
        }
    }
}

// global wrapper for the 3 layer linears
template <typename TA, int RELU, int ROWMAP, int HTW>
__global__ __launch_bounds__(256) void gemmT(
    const TA* __restrict__ A, int lda,
    const short* __restrict__ B, int ldb, int kTiles,
    const float* __restrict__ bias,
    short* __restrict__ C, int ldc, int colofs,
    short* __restrict__ HT) {
    __shared__ __align__(16) short lds[2 * 96 * LDSTR];
    dev_gemmT<TA, RELU, ROWMAP, HTW>(lds, blockIdx.x, blockIdx.y,
                                     A, lda, B, ldb, kTiles, bias, C, ldc, colofs, HT);
}

// ---------------------------------------------------------------------------
// fusedA: mlp2 (512 GEMM blocks, dispatched first) + adjS scaling (2048
// blocks streaming behind). The two parts are fully independent: mlp2 needs
// only W2T (from prepW); adj blocks write adjS for the later gemmS. Overlaps
// the BW-bound adj pass under mlp2's compute instead of serializing launches.
// ---------------------------------------------------------------------------
__global__ __launch_bounds__(256) void fusedA(PrepArgs p,
                                              const float* __restrict__ x,
                                              const float* __restrict__ b_mlp2,
                                              short* __restrict__ big0,
                                              short* __restrict__ HT) {
    __shared__ __align__(16) short lds[2 * 96 * LDSTR];
    int bid = blockIdx.x;
    if (bid < 512) {
        // mlp2: big0[n*4+b][512+d] = x[b*2048+n] @ W2 + b2, fused HT write
        dev_gemmT<float, 0, 1, 1>(lds, bid & 255, bid >> 8,
                                  x, 1536, p.W2T, 1536, 24, b_mlp2,
                                  big0, 640, 512, HT);
        return;
    }
    int row = bid - 512;
    const float* src = p.adj + (size_t)row * 2048;
    float s = 0.f;
    for (int c = threadIdx.x; c < 2048; c += 256) s += src[c];
    float* red = (float*)lds;
    red[threadIdx.x] = s;
    __syncthreads();
    for (int st = 128; st > 0; st >>= 1) {
        if (threadIdx.x < st) red[threadIdx.x] += red[threadIdx.x + st];
        __syncthreads();
    }
    float d = red[0];
    d = d < 1.f ? 1.f : d;
    float inv = 1.f / d;
    short* dst = p.adjS + (size_t)row * 2048;
    for (int c = threadIdx.x; c < 2048; c += 256) dst[c] = to_bf16s(src[c] * inv);
}

// ---------------------------------------------------------------------------
// gemmS: adjacency GEMM partials. R7 structure (64x128 tile, 3-slot 72KB,
// drain-free counted vmcnt, T2 both-sides XOR swizzle) but 512-THREAD blocks:
// same tile, same slots, same traffic -> 2 blocks/CU x 8 waves = 16 waves/CU
// (was 8) for latency hiding. Each wave owns 1 row-frag x 4 col-frags (was
// 2x4); per-wave DMAs per stage = 3 (A 1 + B 2) -> counted wait vmcnt(3).
// Per-output-element accumulation order identical to R7 -> bit-identical.
// ---------------------------------------------------------------------------
__global__ __launch_bounds__(512) void gemmS(const short* __restrict__ A,
                                             const short* __restrict__ B,
                                             short* __restrict__ C) {
    __shared__ __align__(16) short lds3[3 * 12288];  // per slot: As 4096 + Bs 8192

    int tid = threadIdx.x;              // 0..511
    int kz = blockIdx.z * 512;

    // pre-swizzled global source col-group (T2 write side); row = tid>>3 (0..63)
    int kswz = (((tid & 7) ^ ((tid >> 3) & 7))) * 8;
    const short* Ab = A + (size_t)(blockIdx.x * 64 + (tid >> 3)) * 2048 + kz + kswz;
    const short* Bb = B + (size_t)(blockIdx.y * 128 + (tid >> 3)) * 2048 + kz + kswz;

    floatx4 acc[4];
    #pragma unroll
    for (int j = 0; j < 4; ++j)
        #pragma unroll
        for (int r = 0; r < 4; ++r) acc[j][r] = 0.f;

    int lane = tid & 63;
    int w = tid >> 6;                   // 0..7
    int wr = w & 3, wc = w >> 2;        // row-frag 0..3 (16 rows), col-half 0..1
    int quad = lane >> 4, l15 = lane & 15;

    auto stage = [&](int slot, int it) {
        short* As = lds3 + slot * 12288;
        short* Bs = As + 4096;
        const short* Ag = Ab + it * 64;
        const short* Bg = Bb + it * 64;
        dma16(Ag, As + tid * 8);                              // A rows 0..63
        dma16(Bg, Bs + tid * 8);                              // B rows 0..63
        dma16(Bg + (size_t)64 * 2048, Bs + tid * 8 + 4096);   // B rows 64..127
    };

    stage(0, 0);
    stage(1, 1);

    int slot = 0;
    for (int it = 0; it < 8; ++it) {
        if (it < 7) asm volatile("s_waitcnt vmcnt(3)" ::: "memory");
        else        asm volatile("s_waitcnt vmcnt(0)" ::: "memory");
        __builtin_amdgcn_s_barrier();   // raw: prefetch DMAs stay in flight
        if (it + 2 < 8) {
            int s2 = slot + 2; if (s2 >= 3) s2 -= 3;
            stage(s2, it + 2);
        }
        const short* As = lds3 + slot * 12288;
        const short* Bs = As + 4096;
        #pragma unroll
        for (int ks = 0; ks < 2; ++ks) {
            // swizzled read col-group (T2 read side): row&7 == l15&7 for all reads
            int cswz = (((ks * 4 + quad) ^ (l15 & 7))) * 8;
            short8 af = *(const short8*)(As + (wr * 16 + l15) * 64 + cswz);
            short8 bfr[4];
            #pragma unroll
            for (int j = 0; j < 4; ++j)
                bfr[j] = *(const short8*)(Bs + (wc * 64 + j * 16 + l15) * 64 + cswz);
            #pragma unroll
            for (int j = 0; j < 4; ++j)
                acc[j] = __builtin_amdgcn_mfma_f32_16x16x32_bf16(af, bfr[j], acc[j], 0, 0, 0);
        }
        slot = (slot + 1 == 3) ? 0 : slot + 1;
    }

    int colofs = blockIdx.z * 128;
    #pragma unroll
    for (int tj = 0; tj < 4; ++tj) {
        int j = blockIdx.y * 128 + wc * 64 + tj * 16 + l15;  // 0..511 = b*128+d
        int jhi = j >> 7, jlo = j & 127;
        int row0 = blockIdx.x * 64 + wr * 16 + quad * 4;
        #pragma unroll
        for (int r = 0; r < 4; ++r) {
            int m = row0 + r;  // node n
            C[(size_t)(m * 4 + jhi) * 640 + jlo + colofs] = to_bf16s(acc[tj][r]);
        }
    }
}

// ---------------------------------------------------------------------------
// gemmL: mlp1 (R7 verbatim). 128x128 tile, BK=64, dma16, 2-barrier loop,
// T2 both-sides XOR swizzle. fp32 out, row (n*4+b) -> b*2048+n, +bias[col].
// ---------------------------------------------------------------------------
__global__ __launch_bounds__(256) void gemmL(
    const short* __restrict__ A, int lda,
    const short* __restrict__ B, int ldb,
    int kChunkIters, const float* __restrict__ bias,
    float* __restrict__ Cf, int ldc) {
    __shared__ __align__(16) short As[128 * 64];
    __shared__ __align__(16) short Bs[128 * 64];

    int tid = threadIdx.x;
    int blockM = blockIdx.x * 128;
    int blockN = blockIdx.y * 128;

    // pre-swizzled global source col-group (T2 write side)
    int kswz = (((tid & 7) ^ ((tid >> 3) & 7))) * 8;
    const short* Ab = A + (size_t)(blockM + (tid >> 3)) * lda + kswz;
    const short* Bb = B + (size_t)(blockN + (tid >> 3)) * ldb + kswz;
    short* Al = As + tid * 8;
    short* Bl = Bs + tid * 8;

    floatx4 acc[4][4];
    #pragma unroll
    for (int i = 0; i < 4; ++i)
        #pragma unroll
        for (int j = 0; j < 4; ++j)
            #pragma unroll
            for (int r = 0; r < 4; ++r) acc[i][j][r] = 0.f;

    int lane = tid & 63;
    int w = tid >> 6;
    int wr = w >> 1, wc = w & 1;
    int quad = lane >> 4, l15 = lane & 15;

    for (int it = 0; it < kChunkIters; ++it) {
        const short* Ag = Ab + it * 64;
        const short* Bg = Bb + it * 64;
        #pragma unroll
        for (int r = 0; r < 4; ++r) {
            dma16(Ag + (size_t)r * 32 * lda, Al + r * 2048);
            dma16(Bg + (size_t)r * 32 * ldb, Bl + r * 2048);
        }
        __syncthreads();
        #pragma unroll
        for (int ks = 0; ks < 2; ++ks) {
            // swizzled read col-group (T2 read side)
            int cswz = (((ks * 4 + quad) ^ (l15 & 7))) * 8;
            short8 af[4], bfr[4];
            #pragma unroll
            for (int i = 0; i < 4; ++i)
                af[i] = *(const short8*)(As + (wr * 64 + i * 16 + l15) * 64 + cswz);
            #pragma unroll
            for (int j = 0; j < 4; ++j)
                bfr[j] = *(const short8*)(Bs + (wc * 64 + j * 16 + l15) * 64 + cswz);
            #pragma unroll
            for (int i = 0; i < 4; ++i)
                #pragma unroll
                for (int j = 0; j < 4; ++j)
                    acc[i][j] = __builtin_amdgcn_mfma_f32_16x16x32_bf16(af[i], bfr[j], acc[i][j], 0, 0, 0);
        }
        __syncthreads();
    }

    #pragma unroll
    for (int ti = 0; ti < 4; ++ti) {
        #pragma unroll
        for (int tj = 0; tj < 4; ++tj) {
            int col = blockN + wc * 64 + tj * 16 + l15;
            float bv = bias[col];
            int row0 = blockM + wr * 64 + ti * 16 + quad * 4;
            #pragma unroll
            for (int r = 0; r < 4; ++r) {
                int mp = row0 + r;  // n*4+b
                int orow = ((mp & 3) << 11) | (mp >> 2);
                Cf[(size_t)orow * ldc + col] = acc[ti][tj][r] + bv;
            }
        }
    }
}

// ---------------------------------------------------------------------------
// Launch: prepW, fusedA(mlp2 || adjS), (S,T)x3, L  = 9 launches
// ---------------------------------------------------------------------------
extern "C" void kernel_launch(void* const* d_in, const int* in_sizes, int n_in,
                              void* d_out, int out_size, void* d_ws, size_t ws_size,
                              hipStream_t stream) {
    const float* x      = (const float*)d_in[0];
    const float* adj    = (const float*)d_in[1];
    const float* W_mlp2 = (const float*)d_in[2];
    const float* b_mlp2 = (const float*)d_in[3];
    const float* Wr1    = (const float*)d_in[4];
    const float* Wo1    = (const float*)d_in[5];
    const float* b1     = (const float*)d_in[6];
    const float* Wr2    = (const float*)d_in[7];
    const float* Wo2    = (const float*)d_in[8];
    const float* b2     = (const float*)d_in[9];
    const float* Wr3    = (const float*)d_in[10];
    const float* Wo3    = (const float*)d_in[11];
    const float* b3     = (const float*)d_in[12];
    const float* W_mlp1 = (const float*)d_in[13];
    const float* b_mlp1 = (const float*)d_in[14];
    float* out = (float*)d_out;

    char* ws = (char*)d_ws;
    size_t off = 0;
    auto alloc = [&](size_t bytes) -> char* {
        char* p = ws + off;
        off = (off + bytes + 255) & ~(size_t)255;
        return p;
    };
    short* W2T  = (short*)alloc(128 * 1536 * 2);
    short* W1T  = (short*)alloc(1536 * 128 * 2);
    short* BigB[3];
    for (int l = 0; l < 3; ++l) BigB[l] = (short*)alloc(128 * 640 * 2);
    short* adjS = (short*)alloc((size_t)2048 * 2048 * 2);
    short* big[4];
    for (int l = 0; l < 4; ++l) big[l] = (short*)alloc((size_t)8192 * 640 * 2);
    short* HT = (short*)alloc((size_t)512 * 2048 * 2);

    dim3 blk(256);

    PrepArgs pa{adj, W_mlp2, W_mlp1, Wr1, Wo1, Wr2, Wo2, Wr3, Wo3,
                adjS, W2T, W1T, BigB[0], BigB[1], BigB[2]};
    prepW<<<480, blk, 0, stream>>>(pa);

    // mlp2 (512 blocks, first in dispatch order) || adjS scaling (2048 blocks)
    fusedA<<<2560, blk, 0, stream>>>(pa, x, b_mlp2, big[0], HT);

    for (int l = 0; l < 3; ++l) {
        // big_l[:,0:512] = adjS @ Hp_l partials in 4 K-chunks  (M=2048,N=512,K=2048)
        gemmS<<<dim3(32, 4, 4), dim3(512), 0, stream>>>(adjS, HT, big[l]);
        // Hp_{l+1} = act(big_l @ BigB_l^T + b_l)  (M=8192,N=128,K=640), fused HT
        if (l == 0)
            gemmT<short, 1, 0, 1><<<dim3(256, 2), blk, 0, stream>>>(
                big[0], 640, BigB[0], 640, 10, b1, big[1], 640, 512, HT);
        else if (l == 1)
            gemmT<short, 1, 0, 1><<<dim3(256, 2), blk, 0, stream>>>(
                big[1], 640, BigB[1], 640, 10, b2, big[2], 640, 512, HT);
        else
            gemmT<short, 0, 0, 0><<<dim3(256, 2), blk, 0, stream>>>(
                big[2], 640, BigB[2], 640, 10, b3, big[3], 640, 512, nullptr);
    }

    // mlp1: out[b*2048+n] = Hp3 @ W1 + b1   (M=8192,N=1536,K=128)
    gemmL<<<dim3(64, 12), blk, 0, stream>>>(big[3] + 512, 640, W1T, 128, 2, b_mlp1, out, 1536);
}